// Round 6
// baseline (2190.639 us; speedup 1.0000x reference)
//
#include <hip/hip_runtime.h>
#include <stdint.h>

#define LOG2F 0.693147180559945f

// shifted softplus: softplus(x) - log(2), stable form
__device__ __forceinline__ float ssp(float x){
  float t = __expf(-fabsf(x));
  return fmaxf(x, 0.0f) + __logf(1.0f + t) - LOG2F;
}

// ============================================================================
// Scheme: thread = output feature column (128 threads/block), 16 rows/block.
// GEMM Y[r][n] = sum_k A[r][k] * W[k*128 + n]:  k-outer, W read coalesced
// straight from global (row-major, NO transpose), A-row staged in LDS and
// read as broadcast float4. All f32 end-to-end; OUTPUT IS FLOAT32.
// Workspace = vacc (N*128 f32) ONLY.
// ============================================================================

// ---------- edge kernel: vacc[idx_i] += ssp(ssp(x)[idx_j]@Wj + bj) * (g@Wg) ----------
__global__ __launch_bounds__(128) void k_edge(
    const float* __restrict__ x, const float* __restrict__ g,
    const int* __restrict__ idx_i, const int* __restrict__ idx_j,
    const float* __restrict__ Wj, const float* __restrict__ Wg,
    const float* __restrict__ bj, float* __restrict__ vacc,
    int E)
{
  __shared__ __align__(16) float arow[16][128];
  __shared__ __align__(16) float grow[16][32];
  const int tid = threadIdx.x;
  const int e0 = blockIdx.x * 16;

  // stage gathered, activated source rows: arow[r][:] = ssp(x[idx_j[e0+r]][:])
  for (int r = 0; r < 16; ++r){
    int e = e0 + r; if (e >= E) e = E - 1;
    int j = idx_j[e];
    arow[r][tid] = ssp(x[(size_t)j*128 + tid]);
  }
  // stage RBF rows: grow[r][:] = g[e0+r][:]
  for (int i = tid; i < 16*32; i += 128){
    int r = i >> 5, c = i & 31;
    int e = e0 + r; if (e >= E) e = E - 1;
    grow[r][c] = g[(size_t)e*32 + c];
  }
  __syncthreads();

  float am[16], ag[16];
#pragma unroll
  for (int r = 0; r < 16; ++r){ am[r] = 0.f; ag[r] = 0.f; }

  // message GEMM: am[r] = sum_k arow[r][k] * Wj[k][tid]
  for (int k4 = 0; k4 < 32; ++k4){
    float w0 = Wj[(k4*4 + 0)*128 + tid];
    float w1 = Wj[(k4*4 + 1)*128 + tid];
    float w2 = Wj[(k4*4 + 2)*128 + tid];
    float w3 = Wj[(k4*4 + 3)*128 + tid];
#pragma unroll
    for (int r = 0; r < 16; ++r){
      float4 a = *(const float4*)&arow[r][k4*4];
      am[r] += a.x*w0 + a.y*w1 + a.z*w2 + a.w*w3;
    }
  }
  // gate GEMM: ag[r] = sum_k grow[r][k] * Wg[k][tid]
  for (int k4 = 0; k4 < 8; ++k4){
    float w0 = Wg[(k4*4 + 0)*128 + tid];
    float w1 = Wg[(k4*4 + 1)*128 + tid];
    float w2 = Wg[(k4*4 + 2)*128 + tid];
    float w3 = Wg[(k4*4 + 3)*128 + tid];
#pragma unroll
    for (int r = 0; r < 16; ++r){
      float4 a = *(const float4*)&grow[r][k4*4];
      ag[r] += a.x*w0 + a.y*w1 + a.z*w2 + a.w*w3;
    }
  }

  const float bjv = bj[tid];
  for (int r = 0; r < 16; ++r){
    int e = e0 + r;
    if (e < E){
      float vp = ssp(am[r] + bjv) * ag[r];
      atomicAdd(&vacc[(size_t)idx_i[e]*128 + tid], vp);
    }
  }
}

// ---------- fused atom-side chain (float32 output) ----------
__global__ __launch_bounds__(128) void k_chain(
    const float* __restrict__ x, const float* __restrict__ vacc,
    const float* __restrict__ Wi, const float* __restrict__ bi,
    const float* __restrict__ Wf, const float* __restrict__ bf_,
    const float* __restrict__ u,
    const float* __restrict__ Wint, const float* __restrict__ bint,
    const float* __restrict__ Watm, const float* __restrict__ batm,
    const float* __restrict__ Wout, const float* __restrict__ bout,
    float* __restrict__ out, int N, int ni, int na, int no)
{
  __shared__ __align__(16) float arow[16][128];
  const int tid = threadIdx.x;
  const int r0 = blockIdx.x * 16;

  float xar[16], vreg[16], hreg[16], acc[16];

  // arow = xa = ssp(x rows); keep a copy in registers for xp = u*xa
  for (int r = 0; r < 16; ++r){
    int row = r0 + r; if (row >= N) row = N - 1;
    float xav = ssp(x[(size_t)row*128 + tid]);
    xar[r] = xav;
    arow[r][tid] = xav;
  }
  __syncthreads();

  auto gemm = [&](const float* __restrict__ W){
#pragma unroll
    for (int r = 0; r < 16; ++r) acc[r] = 0.f;
    for (int k4 = 0; k4 < 32; ++k4){
      float w0 = W[(k4*4 + 0)*128 + tid];
      float w1 = W[(k4*4 + 1)*128 + tid];
      float w2 = W[(k4*4 + 2)*128 + tid];
      float w3 = W[(k4*4 + 3)*128 + tid];
#pragma unroll
      for (int r = 0; r < 16; ++r){
        float4 a = *(const float4*)&arow[r][k4*4];
        acc[r] += a.x*w0 + a.y*w1 + a.z*w2 + a.w*w3;
      }
    }
  };

  // layer 0: v = vacc + ssp(xa @ Wi + bi)
  gemm(Wi);
  {
    const float bv = bi[tid];
    for (int r = 0; r < 16; ++r){
      int row = r0 + r; if (row >= N) row = N - 1;
      vreg[r] = vacc[(size_t)row*128 + tid] + ssp(acc[r] + bv);
    }
  }
  __syncthreads();
  for (int r = 0; r < 16; ++r) arow[r][tid] = ssp(vreg[r]);
  __syncthreads();

  // interaction residuals: v = residual(v, Wint[k], bint[k]); arow ends = ssp(v)
  for (int kk = 0; kk < ni; ++kk){
    const float* W = Wint + (size_t)kk * 16384;
    const float bv = bint[kk*128 + tid];
    gemm(W);                                  // ssp(v) @ W
    __syncthreads();
    for (int r = 0; r < 16; ++r) arow[r][tid] = ssp(acc[r] + bv);
    __syncthreads();
    gemm(W);                                  // ssp(h1) @ W
    for (int r = 0; r < 16; ++r) vreg[r] += acc[r] + bv;
    __syncthreads();
    for (int r = 0; r < 16; ++r) arow[r][tid] = ssp(vreg[r]);
    __syncthreads();
  }

  // h = u*xa + ssp(v)@Wf + bf     (arow currently holds ssp(v))
  gemm(Wf);
  {
    const float bv = bf_[tid], uv = u[tid];
    for (int r = 0; r < 16; ++r) hreg[r] = acc[r] + bv + uv * xar[r];
  }
  __syncthreads();
  for (int r = 0; r < 16; ++r) arow[r][tid] = ssp(hreg[r]);
  __syncthreads();

  // atom residuals: h = residual(h, Watm[k], batm[k]); arow ends = ssp(h)
  for (int kk = 0; kk < na; ++kk){
    const float* W = Watm + (size_t)kk * 16384;
    const float bv = batm[kk*128 + tid];
    gemm(W);
    __syncthreads();
    for (int r = 0; r < 16; ++r) arow[r][tid] = ssp(acc[r] + bv);
    __syncthreads();
    gemm(W);
    for (int r = 0; r < 16; ++r) hreg[r] += acc[r] + bv;
    __syncthreads();
    for (int r = 0; r < 16; ++r) arow[r][tid] = ssp(hreg[r]);
    __syncthreads();
  }

  // store h (second tuple element) as FLOAT32
  for (int r = 0; r < 16; ++r){
    int row = r0 + r;
    if (row < N) out[(size_t)N*128 + (size_t)row*128 + tid] = hreg[r];
  }

  // output residuals, evolving hreg as o (arow holds ssp(h))
  for (int kk = 0; kk < no; ++kk){
    const float* W = Wout + (size_t)kk * 16384;
    const float bv = bout[kk*128 + tid];
    gemm(W);
    __syncthreads();
    for (int r = 0; r < 16; ++r) arow[r][tid] = ssp(acc[r] + bv);
    __syncthreads();
    gemm(W);
    for (int r = 0; r < 16; ++r) hreg[r] += acc[r] + bv;
    if (kk + 1 < no){
      __syncthreads();
      for (int r = 0; r < 16; ++r) arow[r][tid] = ssp(hreg[r]);
      __syncthreads();
    }
  }

  // o = ssp(o): store (first tuple element) as FLOAT32
  for (int r = 0; r < 16; ++r){
    int row = r0 + r;
    if (row < N) out[(size_t)row*128 + tid] = ssp(hreg[r]);
  }
}

// ---------- launch ----------
extern "C" void kernel_launch(void* const* d_in, const int* in_sizes, int n_in,
                              void* d_out, int out_size, void* d_ws, size_t ws_size,
                              hipStream_t stream)
{
  const float* x    = (const float*)d_in[0];
  const float* g    = (const float*)d_in[1];
  const float* Wf   = (const float*)d_in[2];
  const float* bf_  = (const float*)d_in[3];
  const float* Wg   = (const float*)d_in[4];
  const float* Wj   = (const float*)d_in[5];
  const float* bj   = (const float*)d_in[6];
  const float* Wi   = (const float*)d_in[7];
  const float* bi   = (const float*)d_in[8];
  const float* u    = (const float*)d_in[9];
  const float* Wint = (const float*)d_in[10];
  const float* bint = (const float*)d_in[11];
  const float* Watm = (const float*)d_in[12];
  const float* batm = (const float*)d_in[13];
  const float* Wout = (const float*)d_in[14];
  const float* bout = (const float*)d_in[15];
  const int* idx_i  = (const int*)d_in[16];
  const int* idx_j  = (const int*)d_in[17];

  const int N  = in_sizes[0] / 128;
  const int E  = in_sizes[16];
  const int ni = in_sizes[10] / 16384;
  const int na = in_sizes[12] / 16384;
  const int no = in_sizes[14] / 16384;

  // workspace: ONLY vacc [N,128] f32 (25.6 MB at N=50000)
  float* vacc = (float*)d_ws;

  hipMemsetAsync(vacc, 0, (size_t)N * 128 * sizeof(float), stream);
  k_edge <<<dim3((E + 15)/16), dim3(128), 0, stream>>>(x, g, idx_i, idx_j,
                                                       Wj, Wg, bj, vacc, E);
  k_chain<<<dim3((N + 15)/16), dim3(128), 0, stream>>>(x, vacc,
                                                       Wi, bi, Wf, bf_, u,
                                                       Wint, bint, Watm, batm, Wout, bout,
                                                       (float*)d_out, N, ni, na, no);
}